// Round 1
// baseline (2095.008 us; speedup 1.0000x reference)
//
#include <hip/hip_runtime.h>

typedef unsigned short u16;
typedef __attribute__((ext_vector_type(8))) short bf16x8;
typedef __attribute__((ext_vector_type(4))) float f32x4;

#define DIMC 256
#define HW   50176
#define WIMG 224
#define NTOK 49

// bf16 weight layout in workspace (element offsets)
#define OFF_QKV 0
#define OFF_K   65536
#define OFF_V   131072
#define OFF_P2  196608
#define OFF_K1  262144
#define OFF_K2  327680
#define OFF_V1  393216
#define OFF_V2  458752
#define OFF_OUT 524288
#define W_ELEMS 589824

__device__ __forceinline__ u16 f2b(float x) {
    unsigned u = __float_as_uint(x);
    unsigned r = (u + 0x7fffu + ((u >> 16) & 1u)) >> 16;   // RNE
    return (u16)r;
}
__device__ __forceinline__ float b2f(u16 h) { return __uint_as_float(((unsigned)h) << 16); }

// [64][256] bf16 slot, XOR-swizzled (col in elements)
__device__ __forceinline__ int swzA(int row, int col) { return row*512 + ((col*2) ^ ((row&7)<<4)); }
// [256][64] bf16 (V transposed)
__device__ __forceinline__ int swzV(int ch, int tok)  { return ch*128  + ((tok*2) ^ ((ch&7)<<4)); }
// [64][32] bf16 per-wave P scratch
__device__ __forceinline__ int swzP(int row, int col) { return row*64  + ((col*2) ^ ((row&3)<<4)); }

// rows 0..63 of A(slot) @ W^T, cols [n0,n0+32); W row-major [*,256] bf16
__device__ __forceinline__ void gemm64x32(const char* As, const u16* W, int n0, int lane,
                                          f32x4 acc[4][2]) {
    const int r = lane & 15, g = lane >> 4;
    #pragma unroll
    for (int fi = 0; fi < 4; fi++)
        #pragma unroll
        for (int fj = 0; fj < 2; fj++)
            acc[fi][fj] = (f32x4){0.f, 0.f, 0.f, 0.f};
    #pragma unroll
    for (int kk = 0; kk < 256; kk += 32) {
        bf16x8 a[4], bb[2];
        #pragma unroll
        for (int fi = 0; fi < 4; fi++)
            a[fi] = *(const bf16x8*)(As + swzA(fi*16 + r, kk + g*8));
        #pragma unroll
        for (int fj = 0; fj < 2; fj++)
            bb[fj] = *(const bf16x8*)(W + (size_t)(n0 + fj*16 + r)*256 + kk + g*8);
        #pragma unroll
        for (int fi = 0; fi < 4; fi++)
            #pragma unroll
            for (int fj = 0; fj < 2; fj++)
                acc[fi][fj] = __builtin_amdgcn_mfma_f32_16x16x32_bf16(a[fi], bb[fj], acc[fi][fj], 0, 0, 0);
    }
}

__global__ void vadw_wc(const float* __restrict__ Wqkv, const float* __restrict__ Wp2,
                        const float* __restrict__ Wk1,  const float* __restrict__ Wk2,
                        const float* __restrict__ Wv1,  const float* __restrict__ Wv2,
                        const float* __restrict__ Wout, u16* __restrict__ wbf) {
    int i = blockIdx.x * 256 + threadIdx.x;
    if (i >= W_ELEMS) return;
    float v;
    if      (i < OFF_P2)  v = Wqkv[i];
    else if (i < OFF_K1)  v = Wp2[i - OFF_P2];
    else if (i < OFF_K2)  v = Wk1[i - OFF_K1];
    else if (i < OFF_V1)  v = Wk2[i - OFF_K2];
    else if (i < OFF_V2)  v = Wv1[i - OFF_V1];
    else if (i < OFF_OUT) v = Wv2[i - OFF_V2];
    else                  v = Wout[i - OFF_OUT];
    wbf[i] = f2b(v);
}

__global__ void vadw_fg(const float* __restrict__ G, float* __restrict__ fglob) {
    const int pc = blockIdx.x;                  // b*256 + c
    const float* plane = G + (size_t)pc * HW;
    float s = 0.f;
    for (int i = threadIdx.x; i < HW; i += 256) s += plane[i];
    #pragma unroll
    for (int d = 1; d < 64; d <<= 1) s += __shfl_xor(s, d);
    __shared__ float wsum[4];
    if ((threadIdx.x & 63) == 0) wsum[threadIdx.x >> 6] = s;
    __syncthreads();
    if (threadIdx.x == 0)
        fglob[pc] = (wsum[0] + wsum[1] + wsum[2] + wsum[3]) * (1.f / (float)HW);
}

__global__ __launch_bounds__(512, 2) void vadw_main(
    const float* __restrict__ G, const float* __restrict__ Vsal, const float* __restrict__ Z,
    const float* __restrict__ Wp1, const float* __restrict__ bp1, const float* __restrict__ bp2,
    const float* __restrict__ bk1, const float* __restrict__ bk2,
    const float* __restrict__ bv1, const float* __restrict__ bv2,
    const float* __restrict__ bqkv, const float* __restrict__ bout,
    const u16* __restrict__ wbf, const float* __restrict__ fglob, float* __restrict__ out)
{
    extern __shared__ char smem[];
    char* s0 = smem;            // Z -> GV -> P scratch
    char* s1 = smem + 32768;    // H/Hk/Hv -> V_t
    char* s2 = smem + 65536;    // (1-psi) -> G -> Q -> F
    char* s3 = smem + 98304;    // GK -> K(gated)

    const int tid  = threadIdx.x;
    const int lane = tid & 63;
    const int wave = tid >> 6;
    const int r = lane & 15, g = lane >> 4;
    const int n0 = wave * 32;

    const int blk = blockIdx.x;
    const int b   = blk >> 10;
    const int win = blk & 1023;
    const int pixbase = ((win >> 5) * 7) * WIMG + (win & 31) * 7;
    const size_t gbase = (size_t)b * DIMC * HW;

    // ---- load Z -> s0 ; H = relu(v*Wp1+bp1) -> s1 ----
    for (int i = tid; i < 64 * DIMC; i += 512) {
        const int tok = i & 63, ch = i >> 6;
        u16 zb = 0, hb = 0;
        if (tok < NTOK) {
            const int pix = pixbase + (tok / 7) * WIMG + (tok % 7);
            zb = f2b(Z[gbase + (size_t)ch * HW + pix]);
            const float v  = Vsal[(size_t)b * HW + pix];
            const float hh = v * Wp1[ch] + bp1[ch];
            hb = f2b(hh > 0.f ? hh : 0.f);
        }
        *(u16*)(s0 + swzA(tok, ch)) = zb;
        *(u16*)(s1 + swzA(tok, ch)) = hb;
    }
    __syncthreads();

    f32x4 acc[4][2];

    // ---- psi: sigmoid(H @ Wp2^T + bp2); store (1-psi) -> s2 ----
    gemm64x32(s1, wbf + OFF_P2, n0, lane, acc);
    #pragma unroll
    for (int fi = 0; fi < 4; fi++)
    #pragma unroll
    for (int fj = 0; fj < 2; fj++)
    #pragma unroll
    for (int rr = 0; rr < 4; rr++) {
        const int row = fi*16 + g*4 + rr, col = n0 + fj*16 + r;
        const float x = acc[fi][fj][rr] + bp2[col];
        const float psi = 1.f / (1.f + __expf(-x));
        *(u16*)(s2 + swzA(row, col)) = (row < NTOK) ? f2b(1.f - psi) : (u16)0;
    }
    __syncthreads();

    // ---- Hk = relu(Z @ Wk1^T + bk1) -> s1 ----
    gemm64x32(s0, wbf + OFF_K1, n0, lane, acc);
    #pragma unroll
    for (int fi = 0; fi < 4; fi++)
    #pragma unroll
    for (int fj = 0; fj < 2; fj++)
    #pragma unroll
    for (int rr = 0; rr < 4; rr++) {
        const int row = fi*16 + g*4 + rr, col = n0 + fj*16 + r;
        float x = acc[fi][fj][rr] + bk1[col];
        x = x > 0.f ? x : 0.f;
        *(u16*)(s1 + swzA(row, col)) = (row < NTOK) ? f2b(x) : (u16)0;
    }
    __syncthreads();

    // ---- GK = sigmoid(Hk @ Wk2^T + bk2) * (1-psi) -> s3 ----
    gemm64x32(s1, wbf + OFF_K2, n0, lane, acc);
    #pragma unroll
    for (int fi = 0; fi < 4; fi++)
    #pragma unroll
    for (int fj = 0; fj < 2; fj++)
    #pragma unroll
    for (int rr = 0; rr < 4; rr++) {
        const int row = fi*16 + g*4 + rr, col = n0 + fj*16 + r;
        const float x = acc[fi][fj][rr] + bk2[col];
        const float sg = 1.f / (1.f + __expf(-x));
        const float p  = b2f(*(const u16*)(s2 + swzA(row, col)));
        *(u16*)(s3 + swzA(row, col)) = (row < NTOK) ? f2b(sg * p) : (u16)0;
    }
    __syncthreads();

    // ---- Hv = relu(Z @ Wv1^T + bv1) -> s1 ----
    gemm64x32(s0, wbf + OFF_V1, n0, lane, acc);
    #pragma unroll
    for (int fi = 0; fi < 4; fi++)
    #pragma unroll
    for (int fj = 0; fj < 2; fj++)
    #pragma unroll
    for (int rr = 0; rr < 4; rr++) {
        const int row = fi*16 + g*4 + rr, col = n0 + fj*16 + r;
        float x = acc[fi][fj][rr] + bv1[col];
        x = x > 0.f ? x : 0.f;
        *(u16*)(s1 + swzA(row, col)) = (row < NTOK) ? f2b(x) : (u16)0;
    }
    __syncthreads();

    // ---- GV = sigmoid(Hv @ Wv2^T + bv2) * (1-psi) -> s0 (Z dead) ----
    gemm64x32(s1, wbf + OFF_V2, n0, lane, acc);
    #pragma unroll
    for (int fi = 0; fi < 4; fi++)
    #pragma unroll
    for (int fj = 0; fj < 2; fj++)
    #pragma unroll
    for (int rr = 0; rr < 4; rr++) {
        const int row = fi*16 + g*4 + rr, col = n0 + fj*16 + r;
        const float x = acc[fi][fj][rr] + bv2[col];
        const float sg = 1.f / (1.f + __expf(-x));
        const float p  = b2f(*(const u16*)(s2 + swzA(row, col)));
        *(u16*)(s0 + swzA(row, col)) = (row < NTOK) ? f2b(sg * p) : (u16)0;
    }
    __syncthreads();

    // ---- load G -> s2 ((1-psi) dead) ----
    for (int i = tid; i < 64 * DIMC; i += 512) {
        const int tok = i & 63, ch = i >> 6;
        u16 gb = 0;
        if (tok < NTOK) {
            const int pix = pixbase + (tok / 7) * WIMG + (tok % 7);
            gb = f2b(G[gbase + (size_t)ch * HW + pix]);
        }
        *(u16*)(s2 + swzA(tok, ch)) = gb;
    }
    __syncthreads();

    // ---- K = (G @ Wk_qkv^T + bqkv[256+]) * GK -> s3 (in-place, self-owned) ----
    gemm64x32(s2, wbf + OFF_K, n0, lane, acc);
    #pragma unroll
    for (int fi = 0; fi < 4; fi++)
    #pragma unroll
    for (int fj = 0; fj < 2; fj++)
    #pragma unroll
    for (int rr = 0; rr < 4; rr++) {
        const int row = fi*16 + g*4 + rr, col = n0 + fj*16 + r;
        const float gk = b2f(*(const u16*)(s3 + swzA(row, col)));
        const float x  = (acc[fi][fj][rr] + bqkv[256 + col]) * gk;
        *(u16*)(s3 + swzA(row, col)) = (row < NTOK) ? f2b(x) : (u16)0;
    }
    __syncthreads();

    // ---- V = (G @ Wv_qkv^T + bqkv[512+]) * GV -> s1 TRANSPOSED (Hv dead) ----
    gemm64x32(s2, wbf + OFF_V, n0, lane, acc);
    #pragma unroll
    for (int fi = 0; fi < 4; fi++)
    #pragma unroll
    for (int fj = 0; fj < 2; fj++)
    #pragma unroll
    for (int rr = 0; rr < 4; rr++) {
        const int row = fi*16 + g*4 + rr, col = n0 + fj*16 + r;
        const float gv = b2f(*(const u16*)(s0 + swzA(row, col)));
        const float x  = (acc[fi][fj][rr] + bqkv[512 + col]) * gv;
        *(u16*)(s1 + swzV(col, row)) = (row < NTOK) ? f2b(x) : (u16)0;
    }
    __syncthreads();

    // ---- Q = G @ Wq_qkv^T + bqkv -> s2 in-place (barrier: all reads of G done first) ----
    gemm64x32(s2, wbf + OFF_QKV, n0, lane, acc);
    __syncthreads();
    #pragma unroll
    for (int fi = 0; fi < 4; fi++)
    #pragma unroll
    for (int fj = 0; fj < 2; fj++)
    #pragma unroll
    for (int rr = 0; rr < 4; rr++) {
        const int row = fi*16 + g*4 + rr, col = n0 + fj*16 + r;
        const float x = acc[fi][fj][rr] + bqkv[col];
        *(u16*)(s2 + swzA(row, col)) = (row < NTOK) ? f2b(x) : (u16)0;
    }
    __syncthreads();

    // ---- attention: wave = head (all operands self-owned by col/row slices) ----
    {
        const int n0h = wave * 32;
        f32x4 sc[4][4];
        bf16x8 qa[4], kb[4];
        #pragma unroll
        for (int fi = 0; fi < 4; fi++)
            qa[fi] = *(const bf16x8*)(s2 + swzA(fi*16 + r, n0h + g*8));
        #pragma unroll
        for (int fj = 0; fj < 4; fj++)
            kb[fj] = *(const bf16x8*)(s3 + swzA(fj*16 + r, n0h + g*8));
        #pragma unroll
        for (int fi = 0; fi < 4; fi++)
            #pragma unroll
            for (int fj = 0; fj < 4; fj++)
                sc[fi][fj] = __builtin_amdgcn_mfma_f32_16x16x32_bf16(qa[fi], kb[fj],
                                (f32x4){0.f,0.f,0.f,0.f}, 0, 0, 0);

        const float SCALE = 0.17677669529663687f;   // 32^-0.5
        #pragma unroll
        for (int fi = 0; fi < 4; fi++)
        #pragma unroll
        for (int rr = 0; rr < 4; rr++) {
            float vals[4]; float mx = -1e30f;
            #pragma unroll
            for (int fj = 0; fj < 4; fj++) {
                float v = sc[fi][fj][rr] * SCALE;
                if (fj*16 + r >= NTOK) v = -1e30f;
                vals[fj] = v; mx = fmaxf(mx, v);
            }
            #pragma unroll
            for (int d = 1; d < 16; d <<= 1) mx = fmaxf(mx, __shfl_xor(mx, d));
            float sum = 0.f;
            #pragma unroll
            for (int fj = 0; fj < 4; fj++) { vals[fj] = __expf(vals[fj] - mx); sum += vals[fj]; }
            #pragma unroll
            for (int d = 1; d < 16; d <<= 1) sum += __shfl_xor(sum, d);
            const float inv = 1.f / sum;
            #pragma unroll
            for (int fj = 0; fj < 4; fj++) sc[fi][fj][rr] = vals[fj] * inv;
        }

        // PV in two 32-token halves via per-wave P scratch (C-layout -> A-layout)
        char* scr = s0 + wave * 4096;
        f32x4 facc[4][2];
        #pragma unroll
        for (int fi = 0; fi < 4; fi++)
            #pragma unroll
            for (int fj = 0; fj < 2; fj++)
                facc[fi][fj] = (f32x4){0.f,0.f,0.f,0.f};
        #pragma unroll
        for (int pass = 0; pass < 2; pass++) {
            #pragma unroll
            for (int fi = 0; fi < 4; fi++)
            #pragma unroll
            for (int fl = 0; fl < 2; fl++)
            #pragma unroll
            for (int rr = 0; rr < 4; rr++) {
                const int row = fi*16 + g*4 + rr, col = fl*16 + r;
                *(u16*)(scr + swzP(row, col)) = f2b(sc[fi][pass*2 + fl][rr]);
            }
            bf16x8 pa[4], vb[2];
            #pragma unroll
            for (int fi = 0; fi < 4; fi++)
                pa[fi] = *(const bf16x8*)(scr + swzP(fi*16 + r, g*8));
            #pragma unroll
            for (int fj = 0; fj < 2; fj++)
                vb[fj] = *(const bf16x8*)(s1 + swzV(n0h + fj*16 + r, pass*32 + g*8));
            #pragma unroll
            for (int fi = 0; fi < 4; fi++)
                #pragma unroll
                for (int fj = 0; fj < 2; fj++)
                    facc[fi][fj] = __builtin_amdgcn_mfma_f32_16x16x32_bf16(pa[fi], vb[fj], facc[fi][fj], 0, 0, 0);
        }

        // fused = 0.5*f + 0.5*f_global -> F into s2 (own cols)
        const float fg0 = fglob[b*256 + n0h + r];
        const float fg1 = fglob[b*256 + n0h + 16 + r];
        #pragma unroll
        for (int fi = 0; fi < 4; fi++)
        #pragma unroll
        for (int fj = 0; fj < 2; fj++)
        #pragma unroll
        for (int rr = 0; rr < 4; rr++) {
            const int row = fi*16 + g*4 + rr, ch = n0h + fj*16 + r;
            const float val = 0.5f * (facc[fi][fj][rr] + (fj ? fg1 : fg0));
            *(u16*)(s2 + swzA(row, ch)) = (row < NTOK) ? f2b(val) : (u16)0;
        }
    }
    __syncthreads();

    // ---- out = F @ Wout^T + bout -> global ----
    gemm64x32(s2, wbf + OFF_OUT, n0, lane, acc);
    #pragma unroll
    for (int fi = 0; fi < 4; fi++)
    #pragma unroll
    for (int fj = 0; fj < 2; fj++)
    #pragma unroll
    for (int rr = 0; rr < 4; rr++) {
        const int row = fi*16 + g*4 + rr;
        if (row < NTOK) {
            const int col = n0 + fj*16 + r;
            const int pix = pixbase + (row / 7) * WIMG + (row % 7);
            out[gbase + (size_t)col * HW + pix] = acc[fi][fj][rr] + bout[col];
        }
    }
}

extern "C" void kernel_launch(void* const* d_in, const int* in_sizes, int n_in,
                              void* d_out, int out_size, void* d_ws, size_t ws_size,
                              hipStream_t stream) {
    const float* G    = (const float*)d_in[0];
    // d_in[1] = p_sal: unused by the reference
    const float* Vs   = (const float*)d_in[2];
    const float* Z    = (const float*)d_in[3];
    const float* Wqkv = (const float*)d_in[4];
    const float* bqkv = (const float*)d_in[5];
    const float* Wout = (const float*)d_in[6];
    const float* bout = (const float*)d_in[7];
    const float* Wk1  = (const float*)d_in[8];
    const float* bk1  = (const float*)d_in[9];
    const float* Wk2  = (const float*)d_in[10];
    const float* bk2  = (const float*)d_in[11];
    const float* Wv1  = (const float*)d_in[12];
    const float* bv1  = (const float*)d_in[13];
    const float* Wv2  = (const float*)d_in[14];
    const float* bv2  = (const float*)d_in[15];
    const float* Wp1  = (const float*)d_in[16];
    const float* bp1  = (const float*)d_in[17];
    const float* Wp2  = (const float*)d_in[18];
    const float* bp2  = (const float*)d_in[19];
    float* out    = (float*)d_out;
    float* fglob  = (float*)d_ws;
    u16*   wbf    = (u16*)((char*)d_ws + 4096);

    vadw_wc<<<W_ELEMS / 256, 256, 0, stream>>>(Wqkv, Wp2, Wk1, Wk2, Wv1, Wv2, Wout, wbf);
    vadw_fg<<<1024, 256, 0, stream>>>(G, fglob);
    hipFuncSetAttribute(reinterpret_cast<const void*>(vadw_main),
                        hipFuncAttributeMaxDynamicSharedMemorySize, 131072);
    vadw_main<<<4096, 512, 131072, stream>>>(G, Vs, Z, Wp1, bp1, bp2, bk1, bk2, bv1, bv2,
                                             bqkv, bout, wbf, fglob, out);
}